// Round 1
// baseline (1816.017 us; speedup 1.0000x reference)
//
#include <hip/hip_runtime.h>
#include <math.h>

// ---------------------------------------------------------------------------
// LNN-first transformer, MI355X. B=16 T=1024 H=256 NH=4 dh=64 FF=1024 L=2
// Arena layout in d_ws (assumes ws_size >= 88MB):
//   A   @  0MB (16MB) : ip (T,B,H) f32, later raw GEMM out (tok,H) f32
//   B   @ 16MB (16MB) : seqF (B,T,H) f32   (residual stream)
//   C   @ 32MB ( 8MB) : u / seqB (B,T,H) bf16 (GEMM A operand)
//   Q   @ 40MB ( 8MB) : Q (B*NH,T,64) bf16     } ff1 (tok,FF) bf16 reuses
//   K   @ 48MB ( 8MB) : K (B*NH,T,64) bf16     } 40..72MB after attention
//   V   @ 56MB ( 8MB) : V (B*NH,T,64) bf16     }
//   VT  @ 64MB ( 8MB) : V^T (B*NH,64,T) bf16   }
//   CTX @ 72MB ( 8MB) : attn out (B,T,H) bf16
//   WB  @ 80MB ( 4MB) : all weights converted to bf16
// ---------------------------------------------------------------------------

typedef unsigned short u16;
typedef __attribute__((ext_vector_type(4))) float f32x4;
typedef __attribute__((ext_vector_type(8))) short s16x8;
typedef __attribute__((ext_vector_type(4))) unsigned short u16x4;
typedef __attribute__((ext_vector_type(8))) unsigned short u16x8;

#define DEV static __device__ __forceinline__

DEV u16 f2bf(float f){
  unsigned u = __float_as_uint(f);
  u = (u + 0x7FFFu + ((u>>16)&1u)) >> 16;   // RNE
  return (u16)u;
}

DEV f32x4 mfma16(s16x8 a, s16x8 b, f32x4 c){
  return __builtin_amdgcn_mfma_f32_16x16x32_bf16(a,b,c,0,0,0);
}

DEV float wave_sum64(float v){
  #pragma unroll
  for(int o=1;o<64;o<<=1) v += __shfl_xor(v,o,64);
  return v;
}

DEV float geluf(float x){ return 0.5f*x*(1.f+erff(x*0.70710678118654752f)); }

// --------------------------- weight fp32 -> bf16 ----------------------------
// concatenated: W_x(65536) Wqkv(393216) Wo(131072) W1(524288) W2(524288)
#define WB_WX   0
#define WB_WQKV 65536
#define WB_WO   458752
#define WB_W1   589824
#define WB_W2   1114112
#define WB_TOT  1638400

__global__ __launch_bounds__(256) void k_wconv(const float* __restrict__ wx,
    const float* __restrict__ wqkv, const float* __restrict__ wo,
    const float* __restrict__ w1, const float* __restrict__ w2,
    u16* __restrict__ out){
  int i = (blockIdx.x*256 + threadIdx.x)*4;
  const float* src; int off;
  if(i < WB_WQKV){ src=wx;   off=i; }
  else if(i < WB_WO ){ src=wqkv; off=i-WB_WQKV; }
  else if(i < WB_W1 ){ src=wo;   off=i-WB_WO; }
  else if(i < WB_W2 ){ src=w1;   off=i-WB_W1; }
  else              { src=w2;   off=i-WB_W2; }
  f32x4 v = *(const f32x4*)(src+off);
  u16x4 o; 
  #pragma unroll
  for(int j=0;j<4;++j) o[j]=f2bf(v[j]);
  *(u16x4*)(out+i)=o;
}

// ------------------- input proj + LN + GELU -> u (bf16) ---------------------
__global__ __launch_bounds__(256) void k_input(const float* __restrict__ x,
    const float* __restrict__ W_in, const float* __restrict__ b_in,
    const float* __restrict__ g, const float* __restrict__ bt,
    u16* __restrict__ uout){
  int tid=threadIdx.x; int w=tid>>6; int la=tid&63;
  int tok = blockIdx.x*4 + w;
  float xv = x[tok];
  f32x4 wv = *(const f32x4*)(W_in + la*4);
  f32x4 bv = *(const f32x4*)(b_in + la*4);
  float v[4]; float s=0.f;
  #pragma unroll
  for(int j=0;j<4;++j){ v[j]=xv*wv[j]+bv[j]; s+=v[j]; }
  s = wave_sum64(s);
  float m = s*(1.f/256.f);
  float ss=0.f;
  #pragma unroll
  for(int j=0;j<4;++j){ v[j]-=m; ss+=v[j]*v[j]; }
  ss = wave_sum64(ss);
  float rs = rsqrtf(ss*(1.f/256.f)+1e-5f);
  f32x4 gv=*(const f32x4*)(g+la*4), tv=*(const f32x4*)(bt+la*4);
  u16x4 o;
  #pragma unroll
  for(int j=0;j<4;++j){ float y=v[j]*rs*gv[j]+tv[j]; o[j]=f2bf(geluf(y)); }
  *(u16x4*)(uout + (size_t)tok*256 + la*4) = o;
}

// ------------------------------- GEMM ---------------------------------------
// out(M,N) = A(M,K) @ W(N,K)^T + bias, 128x128 tile, 4 waves of 64x64,
// direct-from-global fragments (both operands are row-contiguous in K).
// EPI: 0=store ip f32 (T,B,H); 1=QKV split to head layout bf16;
//      2=+residual f32; 3=GELU bf16 (FF=1024 cols)
template<int EPI, int K>
__global__ __launch_bounds__(256) void k_gemm(const u16* __restrict__ A,
    const u16* __restrict__ W, const float* __restrict__ bias,
    const float* __restrict__ res, float* __restrict__ oF,
    u16* __restrict__ o0, u16* __restrict__ o1, u16* __restrict__ o2){
  int tid=threadIdx.x; int w=tid>>6; int wr=w>>1, wc=w&1;
  int la=tid&63, lq=la>>4, lr=la&15;
  int rb=blockIdx.x*128+wr*64, cb=blockIdx.y*128+wc*64;
  f32x4 acc[4][4];
  #pragma unroll
  for(int mt=0;mt<4;++mt)
    #pragma unroll
    for(int nt=0;nt<4;++nt) acc[mt][nt]=f32x4{0.f,0.f,0.f,0.f};
  const u16* Ap = A + (size_t)(rb+lr)*K + lq*8;
  const u16* Wp = W + (size_t)(cb+lr)*K + lq*8;
  #pragma unroll 8
  for(int kk=0;kk<K/32;++kk){
    s16x8 aF[4], bF[4];
    #pragma unroll
    for(int mt=0;mt<4;++mt) aF[mt]=*(const s16x8*)(Ap + (size_t)mt*16*K + kk*32);
    #pragma unroll
    for(int nt=0;nt<4;++nt) bF[nt]=*(const s16x8*)(Wp + (size_t)nt*16*K + kk*32);
    #pragma unroll
    for(int mt=0;mt<4;++mt)
      #pragma unroll
      for(int nt=0;nt<4;++nt) acc[mt][nt]=mfma16(aF[mt],bF[nt],acc[mt][nt]);
  }
  #pragma unroll
  for(int mt=0;mt<4;++mt){
    #pragma unroll
    for(int nt=0;nt<4;++nt){
      int col = cb+nt*16+lr;
      float bv = bias[col];
      #pragma unroll
      for(int i=0;i<4;++i){
        int row = rb+mt*16+lq*4+i;
        float v = acc[mt][nt][i]+bv;
        if constexpr(EPI==0){
          int b=row>>10, t=row&1023;
          oF[((size_t)(t*16+b))*256+col]=v;
        } else if constexpr(EPI==1){
          int sec=col>>8; int h=col&255; int head=h>>6, d=h&63;
          int b=row>>10, t=row&1023;
          size_t adr=((size_t)((b*4+head)*1024+t))*64+d;
          u16 q=f2bf(v);
          if(sec==0) o0[adr]=q; else if(sec==1) o1[adr]=q; else o2[adr]=q;
        } else if constexpr(EPI==2){
          size_t adr=(size_t)row*256+col;
          oF[adr]=v+res[adr];
        } else {
          o0[(size_t)row*1024+col]=f2bf(geluf(v));
        }
      }
    }
  }
}

// ------------------------------- LNN scan -----------------------------------
// 1 workgroup, 8 waves. Wave w owns output cols [32w,32w+32). W_rec held as
// B-fragments in registers. h (16x256 bf16) double-buffered in LDS, XOR-swizzled.
__global__ __launch_bounds__(512) void k_scan(const float* __restrict__ ip,
    const float* __restrict__ W_rec, const float* __restrict__ tau,
    float* __restrict__ seqF, u16* __restrict__ seqB){
  __shared__ u16 hbuf[2][4096];
  int tid=threadIdx.x, w=tid>>6, la=tid&63, lq=la>>4, lr=la&15;
  for(int i=tid;i<8192;i+=512) ((u16*)hbuf)[i]=0;
  int col[2]; float aC[2];
  s16x8 bF[2][8];
  #pragma unroll
  for(int nt=0;nt<2;++nt){
    int c = w*32+nt*16+lr; col[nt]=c;
    aC[nt] = 1.f - 0.1f/tau[c];
    for(int kk=0;kk<8;++kk){
      s16x8 f;
      #pragma unroll
      for(int j=0;j<8;++j){ int k=kk*32+lq*8+j; f[j]=(short)f2bf(W_rec[(size_t)k*256+c]); }
      bF[nt][kk]=f;
    }
  }
  float hC[2][4]={{0,0,0,0},{0,0,0,0}};
  float ipc[2][4], ipn[2][4]={{0,0,0,0},{0,0,0,0}};
  #pragma unroll
  for(int nt=0;nt<2;++nt)
    #pragma unroll
    for(int i=0;i<4;++i) ipc[nt][i]=ip[(size_t)(lq*4+i)*256+col[nt]];
  __syncthreads();
  for(int t=0;t<1024;++t){
    const char* rbuf = (const char*)hbuf + (t&1)*8192;
    char* wbuf = (char*)hbuf + ((t+1)&1)*8192;
    s16x8 aF[8];
    #pragma unroll
    for(int kk=0;kk<8;++kk){
      int off = (lr*512 + kk*64 + lq*16) ^ ((lr&7)<<4);
      aF[kk]=*(const s16x8*)(rbuf+off);
    }
    if(t<1023){
      #pragma unroll
      for(int nt=0;nt<2;++nt)
        #pragma unroll
        for(int i=0;i<4;++i)
          ipn[nt][i]=ip[(size_t)(t+1)*4096 + (lq*4+i)*256 + col[nt]];
    }
    f32x4 acc[2]; acc[0]=f32x4{0.f,0.f,0.f,0.f}; acc[1]=f32x4{0.f,0.f,0.f,0.f};
    #pragma unroll
    for(int kk=0;kk<8;++kk) acc[0]=mfma16(aF[kk],bF[0][kk],acc[0]);
    #pragma unroll
    for(int kk=0;kk<8;++kk) acc[1]=mfma16(aF[kk],bF[1][kk],acc[1]);
    #pragma unroll
    for(int nt=0;nt<2;++nt){
      #pragma unroll
      for(int i=0;i<4;++i){
        float s = ipc[nt][i]+acc[nt][i];
        s = fminf(fmaxf(s,-15.f),15.f);
        float e = __expf(2.f*s);
        float f = 1.f - 2.f*__builtin_amdgcn_rcpf(e+1.f);   // tanh(s)
        float hn = aC[nt]*hC[nt][i] + 0.1f*f;
        hn = fminf(fmaxf(hn,-10.f),10.f);
        hC[nt][i]=hn;
        int b = lq*4+i;
        size_t ga = (((size_t)b<<10)+t)*256 + col[nt];
        seqF[ga]=hn;
        u16 hb=f2bf(hn);
        seqB[ga]=hb;
        int off = (b*512 + col[nt]*2) ^ ((b&7)<<4);
        *(u16*)(wbuf+off)=hb;
      }
    }
    #pragma unroll
    for(int nt=0;nt<2;++nt)
      #pragma unroll
      for(int i=0;i<4;++i) ipc[nt][i]=ipn[nt][i];
    __syncthreads();
  }
}

// ----------------------------- V transpose ----------------------------------
__global__ __launch_bounds__(256) void k_vt(const u16* __restrict__ V, u16* __restrict__ VT){
  __shared__ u16 tile[64][80];
  int tid=threadIdx.x; int bh=blockIdx.y, kvb=blockIdx.x;
  #pragma unroll
  for(int r=0;r<2;++r){
    int kv=(tid>>3)+r*32; int d0=(tid&7)*8;
    *(u16x8*)&tile[kv][d0] = *(const u16x8*)(V + ((size_t)bh*1024+kvb*64+kv)*64 + d0);
  }
  __syncthreads();
  #pragma unroll
  for(int r=0;r<2;++r){
    int d=tid>>2; int ko=(tid&3)+r*4;
    u16x8 o;
    #pragma unroll
    for(int j=0;j<8;++j) o[j]=tile[ko*8+j][d];
    *(u16x8*)(VT + ((size_t)bh*64+d)*1024 + kvb*64 + ko*8) = o;
  }
}

// ------------------------------ attention -----------------------------------
// grid(16 qblocks, 64 bh), 4 waves; wave w: 16 q rows. Swapped QK^T (S^T in
// regs), online softmax over q-columns, P via per-wave LDS, PV from V^T.
__global__ __launch_bounds__(256) void k_attn(const u16* __restrict__ Q,
    const u16* __restrict__ K, const u16* __restrict__ VT, u16* __restrict__ ctx){
  __shared__ u16 pbuf[4][1024];
  int tid=threadIdx.x, w=tid>>6, la=tid&63, lq=la>>4, lr=la&15;
  int bh=blockIdx.y, qb=blockIdx.x;
  int qbase = qb*64 + w*16;
  char* pwc = (char*)pbuf + w*2048;
  const u16* Qp = Q + ((size_t)bh*1024 + qbase + lr)*64 + lq*8;
  s16x8 qF0=*(const s16x8*)Qp, qF1=*(const s16x8*)(Qp+32);
  f32x4 O[4];
  #pragma unroll
  for(int nt=0;nt<4;++nt) O[nt]=f32x4{0.f,0.f,0.f,0.f};
  float m_run=-1e30f, l_run=0.f;
  for(int kvb=0;kvb<16;++kvb){
    int kvbase=kvb*64;
    f32x4 sa[4];
    #pragma unroll
    for(int mt=0;mt<4;++mt){
      const u16* Kp = K + ((size_t)bh*1024 + kvbase + mt*16 + lr)*64 + lq*8;
      s16x8 k0=*(const s16x8*)Kp, k1=*(const s16x8*)(Kp+32);
      f32x4 a=f32x4{0.f,0.f,0.f,0.f};
      a=mfma16(k0,qF0,a); a=mfma16(k1,qF1,a);
      sa[mt]=a;
    }
    float p[4][4]; float pm=-1e30f;
    #pragma unroll
    for(int mt=0;mt<4;++mt)
      #pragma unroll
      for(int i=0;i<4;++i){ p[mt][i]=sa[mt][i]*0.125f; pm=fmaxf(pm,p[mt][i]); }
    pm=fmaxf(pm,__shfl_xor(pm,16,64));
    pm=fmaxf(pm,__shfl_xor(pm,32,64));
    float mnew=fmaxf(m_run,pm);
    float c=__expf(m_run-mnew);
    float ps=0.f;
    #pragma unroll
    for(int mt=0;mt<4;++mt)
      #pragma unroll
      for(int i=0;i<4;++i){ p[mt][i]=__expf(p[mt][i]-mnew); ps+=p[mt][i]; }
    ps+=__shfl_xor(ps,16,64);
    ps+=__shfl_xor(ps,32,64);
    l_run=l_run*c+ps; m_run=mnew;
    #pragma unroll
    for(int i=0;i<4;++i){
      float ci=__shfl(c, lq*4+i, 64);
      #pragma unroll
      for(int nt=0;nt<4;++nt) O[nt][i]*=ci;
    }
    #pragma unroll
    for(int mt=0;mt<4;++mt){
      u16x4 pk;
      #pragma unroll
      for(int i=0;i<4;++i) pk[i]=f2bf(p[mt][i]);
      int off = (lr*128 + mt*32 + lq*8) ^ ((lr&7)<<4);
      *(u16x4*)(pwc+off)=pk;
    }
    #pragma unroll
    for(int kk2=0;kk2<2;++kk2){
      int off = (lr*128 + kk2*64 + lq*16) ^ ((lr&7)<<4);
      s16x8 pA = *(const s16x8*)(pwc+off);
      #pragma unroll
      for(int nt=0;nt<4;++nt){
        const u16* Vp = VT + ((size_t)bh*64 + nt*16 + lr)*1024 + kvbase + kk2*32 + lq*8;
        O[nt]=mfma16(pA, *(const s16x8*)Vp, O[nt]);
      }
    }
  }
  int b=bh>>2, head=bh&3;
  #pragma unroll
  for(int i=0;i<4;++i){
    float li=__shfl(l_run, lq*4+i, 64);
    float inv=1.f/li;
    int t = qb*64 + w*16 + lq*4 + i;
    #pragma unroll
    for(int nt=0;nt<4;++nt){
      ctx[((size_t)(b*1024+t))*256 + head*64 + nt*16 + lr] = f2bf(O[nt][i]*inv);
    }
  }
}

// ------------------------------- LayerNorm ----------------------------------
__global__ __launch_bounds__(256) void k_ln(const float* __restrict__ in,
    const float* __restrict__ g, const float* __restrict__ bt,
    float* __restrict__ outF, u16* __restrict__ outB){
  int tid=threadIdx.x; int w=tid>>6; int la=tid&63;
  int tok = blockIdx.x*4 + w;
  f32x4 v = *(const f32x4*)(in + (size_t)tok*256 + la*4);
  float s=v[0]+v[1]+v[2]+v[3];
  s=wave_sum64(s);
  float m=s*(1.f/256.f);
  float ss=0.f;
  #pragma unroll
  for(int j=0;j<4;++j){ v[j]-=m; ss+=v[j]*v[j]; }
  ss=wave_sum64(ss);
  float rs=rsqrtf(ss*(1.f/256.f)+1e-5f);
  f32x4 gv=*(const f32x4*)(g+la*4), tv=*(const f32x4*)(bt+la*4);
  f32x4 o; u16x4 ob;
  #pragma unroll
  for(int j=0;j<4;++j){ o[j]=v[j]*rs*gv[j]+tv[j]; ob[j]=f2bf(o[j]); }
  *(f32x4*)(outF + (size_t)tok*256 + la*4)=o;
  *(u16x4*)(outB + (size_t)tok*256 + la*4)=ob;
}

// ------------------------------- pool + fc ----------------------------------
__global__ __launch_bounds__(256) void k_pool(const float* __restrict__ seqF,
    const float* __restrict__ W_fc, const float* __restrict__ b_fc,
    float* __restrict__ out){
  int tid=threadIdx.x; int b=blockIdx.y; int t0=blockIdx.x*128;
  float s=0.f;
  for(int tt=0;tt<128;++tt) s += seqF[(((size_t)b<<10)+t0+tt)*256 + tid];
  float v = s * W_fc[tid];
  v = wave_sum64(v);
  __shared__ float red[4];
  if((tid&63)==0) red[tid>>6]=v;
  __syncthreads();
  if(tid==0){
    float tot=red[0]+red[1]+red[2]+red[3];
    atomicAdd(out+b, tot*(1.f/1024.f));
    if(blockIdx.x==0) atomicAdd(out+b, b_fc[0]);
  }
}

// ------------------------------- launch -------------------------------------
extern "C" void kernel_launch(void* const* d_in, const int* in_sizes, int n_in,
                              void* d_out, int out_size, void* d_ws, size_t ws_size,
                              hipStream_t stream){
  const float* x      =(const float*)d_in[0];
  const float* W_in   =(const float*)d_in[1];
  const float* b_in   =(const float*)d_in[2];
  const float* ln_in_g=(const float*)d_in[3];
  const float* ln_in_b=(const float*)d_in[4];
  const float* W_x    =(const float*)d_in[5];
  const float* b_x    =(const float*)d_in[6];
  const float* tau    =(const float*)d_in[7];
  const float* W_rec  =(const float*)d_in[8];
  const float* Wqkv   =(const float*)d_in[9];
  const float* bqkv   =(const float*)d_in[10];
  const float* Wo     =(const float*)d_in[11];
  const float* bo     =(const float*)d_in[12];
  const float* ln1_g  =(const float*)d_in[13];
  const float* ln1_b  =(const float*)d_in[14];
  const float* W1     =(const float*)d_in[15];
  const float* b1     =(const float*)d_in[16];
  const float* W2     =(const float*)d_in[17];
  const float* b2     =(const float*)d_in[18];
  const float* ln2_g  =(const float*)d_in[19];
  const float* ln2_b  =(const float*)d_in[20];
  const float* W_fc   =(const float*)d_in[21];
  const float* b_fc   =(const float*)d_in[22];
  float* out=(float*)d_out;

  char* ws=(char*)d_ws;
  const size_t MB=1ull<<20;
  float* ip   =(float*)(ws);             // also rawO
  float* rawO = ip;
  float* seqF =(float*)(ws+16*MB);
  u16*   seqB =(u16*)  (ws+32*MB);
  u16*   Qb   =(u16*)  (ws+40*MB);
  u16*   Kb   =(u16*)  (ws+48*MB);
  u16*   Vb   =(u16*)  (ws+56*MB);
  u16*   VTb  =(u16*)  (ws+64*MB);
  u16*   ff1  =(u16*)  (ws+40*MB);       // reuses Q..VT after attention
  u16*   ctx  =(u16*)  (ws+72*MB);
  u16*   wb   =(u16*)  (ws+80*MB);

  hipMemsetAsync(d_out, 0, 16*sizeof(float), stream);
  k_wconv<<<WB_TOT/4/256, 256, 0, stream>>>(W_x, Wqkv, Wo, W1, W2, wb);
  k_input<<<4096, 256, 0, stream>>>(x, W_in, b_in, ln_in_g, ln_in_b, seqB);
  // ip = u @ W_x^T + b_x, stored (T,B,H)
  k_gemm<0,256><<<dim3(128,2), 256, 0, stream>>>(seqB, wb+WB_WX, b_x, nullptr, ip, nullptr, nullptr, nullptr);
  k_scan<<<1, 512, 0, stream>>>(ip, W_rec, tau, seqF, seqB);

  for(int ly=0; ly<2; ++ly){
    k_gemm<1,256><<<dim3(128,6), 256, 0, stream>>>(seqB, wb+WB_WQKV+ly*196608, bqkv+ly*768, nullptr, nullptr, Qb, Kb, Vb);
    k_vt  <<<dim3(16,64), 256, 0, stream>>>(Vb, VTb);
    k_attn<<<dim3(16,64), 256, 0, stream>>>(Qb, Kb, VTb, ctx);
    k_gemm<2,256><<<dim3(128,2), 256, 0, stream>>>(ctx, wb+WB_WO+ly*65536, bo+ly*256, seqF, rawO, nullptr, nullptr, nullptr);
    k_ln  <<<4096, 256, 0, stream>>>(rawO, ln1_g+ly*256, ln1_b+ly*256, seqF, seqB);
    k_gemm<3,256><<<dim3(128,8), 256, 0, stream>>>(seqB, wb+WB_W1+ly*262144, b1+ly*1024, nullptr, nullptr, ff1, nullptr, nullptr);
    k_gemm<2,1024><<<dim3(128,2), 256, 0, stream>>>(ff1, wb+WB_W2+ly*262144, b2+ly*256, seqF, rawO, nullptr, nullptr, nullptr);
    k_ln  <<<4096, 256, 0, stream>>>(rawO, ln2_g+ly*256, ln2_b+ly*256, seqF, seqB);
  }
  k_pool<<<dim3(8,16), 256, 0, stream>>>(seqF, W_fc, b_fc, out);
}

// Round 8
// 1225.642 us; speedup vs baseline: 1.4817x; 1.4817x over previous
//
#include <hip/hip_runtime.h>
#include <math.h>

// ---------------------------------------------------------------------------
// LNN-first transformer, MI355X. B=16 T=1024 H=256 NH=4 dh=64 FF=1024 L=2
// Token-major ordering: tok = t*16 + b  for all (B,T,H)-shaped activations.
// MFMA-fragment-tiled layout for all GEMM operands:
//   element (r,k) of an [R,K] operand lives at
//     ((r>>4)*(K/32) + (k>>5))*512 + (((k>>3)&3)*16 + (r&15))*8 + (k&7)
//   -> one wave fragment load = 1KB contiguous.
// Arena (d_ws >= 88MB):
//   A   @  0MB (16MB) : ip (T,B,H) f32 row-major; later rawO (tok,H) f32
//   B   @ 16MB (16MB) : seqF (tok,H) f32 row-major (residual stream)
//   C   @ 32MB ( 8MB) : u / seqB tiled bf16 [16384,256]
//   Q   @ 40MB ( 8MB) : Q tiled per-bh [1024,64]   } ff1 tiled [16384,1024]
//   K   @ 48MB ( 8MB) : K tiled per-bh [1024,64]   } reuses 40..72MB
//   V   @ 56MB ( 8MB) : V row-major per-bh [1024,64]
//   VT  @ 64MB ( 8MB) : V^T tiled per-bh [64,1024]
//   CTX @ 72MB ( 8MB) : attn out tiled [16384,256]
//   WB  @ 80MB ( 4MB) : weights bf16, fragment-tiled
// ---------------------------------------------------------------------------

typedef unsigned short u16;
typedef __attribute__((ext_vector_type(4))) float f32x4;
typedef __attribute__((ext_vector_type(8))) short s16x8;
typedef __attribute__((ext_vector_type(4))) unsigned short u16x4;
typedef __attribute__((ext_vector_type(8))) unsigned short u16x8;

#define DEV static __device__ __forceinline__

DEV u16 f2bf_cvt(float f){
  float r; asm("v_cvt_pk_bf16_f32 %0, %1, %1" : "=v"(r) : "v"(f));
  return (u16)(__float_as_uint(r)&0xFFFFu);
}

DEV f32x4 mfma16(s16x8 a, s16x8 b, f32x4 c){
  return __builtin_amdgcn_mfma_f32_16x16x32_bf16(a,b,c,0,0,0);
}

DEV float wave_sum64(float v){
  #pragma unroll
  for(int o=1;o<64;o<<=1) v += __shfl_xor(v,o,64);
  return v;
}

DEV float geluf(float x){ return 0.5f*x*(1.f+erff(x*0.70710678118654752f)); }

// tiled-address helper: element (r,k) of [R,K] operand, KT = K/32
DEV size_t tadr(int r, int k, int KT){
  return ((size_t)((r>>4)*KT + (k>>5)))*512 + (((k>>3)&3)*16 + (r&15))*8 + (k&7);
}

// --------------------------- weights -> bf16 tiled ---------------------------
// tiled segment bases (u16 elems):
#define WB_WX   0
#define WB_WQKV 65536
#define WB_WO   458752
#define WB_W1   589824
#define WB_W2   1114112

__global__ __launch_bounds__(256) void k_wconv(const float* __restrict__ wx,
    const float* __restrict__ wqkv, const float* __restrict__ wo,
    const float* __restrict__ w1, const float* __restrict__ w2,
    u16* __restrict__ out){
  int g = blockIdx.x*4 + (threadIdx.x>>6);
  int la = threadIdx.x & 63;
  const float* src; int tl, ob, KL=3; // KT log2: K=256 -> KT=8
  if(g<128)      {src=wx;          tl=g;      ob=WB_WX;}
  else if(g<512) {src=wqkv;        tl=g-128;  ob=WB_WQKV;}
  else if(g<896) {src=wqkv+196608; tl=g-512;  ob=262144;}
  else if(g<1024){src=wo;          tl=g-896;  ob=WB_WO;}
  else if(g<1152){src=wo+65536;    tl=g-1024; ob=524288;}
  else if(g<1664){src=w1;          tl=g-1152; ob=WB_W1;}
  else if(g<2176){src=w1+262144;   tl=g-1664; ob=851968;}
  else if(g<2688){src=w2;          tl=g-2176; ob=WB_W2;   KL=5;}
  else           {src=w2+262144;   tl=g-2688; ob=1376256; KL=5;}
  int KT = 1<<KL; int K = KT*32;
  int tr = tl>>KL, tk = tl&(KT-1);
  const float* p = src + (size_t)(tr*16 + (la&15))*K + tk*32 + (la>>4)*8;
  f32x4 v0=*(const f32x4*)p, v1=*(const f32x4*)(p+4);
  s16x8 o;
  #pragma unroll
  for(int j=0;j<4;++j){ o[j]=(short)f2bf_cvt(v0[j]); o[j+4]=(short)f2bf_cvt(v1[j]); }
  *(s16x8*)(out + (size_t)ob + (size_t)tl*512 + la*8) = o;
}

// ------------------- input proj + LN + GELU -> u (tiled bf16) ---------------
__global__ __launch_bounds__(256) void k_input(const float* __restrict__ x,
    const float* __restrict__ W_in, const float* __restrict__ b_in,
    const float* __restrict__ g, const float* __restrict__ bt,
    u16* __restrict__ uout){
  int tid=threadIdx.x; int w=tid>>6; int la=tid&63;
  int tok = blockIdx.x*4 + w;              // token-major: tok = t*16+b
  float xv = x[(tok&15)*1024 + (tok>>4)];  // x is (B,T,1)
  f32x4 wv = *(const f32x4*)(W_in + la*4);
  f32x4 bv = *(const f32x4*)(b_in + la*4);
  float v[4]; float s=0.f;
  #pragma unroll
  for(int j=0;j<4;++j){ v[j]=xv*wv[j]+bv[j]; s+=v[j]; }
  s = wave_sum64(s);
  float m = s*(1.f/256.f);
  float ss=0.f;
  #pragma unroll
  for(int j=0;j<4;++j){ v[j]-=m; ss+=v[j]*v[j]; }
  ss = wave_sum64(ss);
  float rs = rsqrtf(ss*(1.f/256.f)+1e-5f);
  f32x4 gv=*(const f32x4*)(g+la*4), tv=*(const f32x4*)(bt+la*4);
  u16x4 o;
  #pragma unroll
  for(int j=0;j<4;++j){ float y=v[j]*rs*gv[j]+tv[j]; o[j]=f2bf_cvt(geluf(y)); }
  // tiled write: cols la*4..la*4+3
  int off = ((tok>>4)*8 + (la>>3))*512 + (((la>>1)&3)*16 + (tok&15))*8 + (la&1)*4;
  *(u16x4*)(uout + off) = o;
}

// ------------------------------- GEMM ---------------------------------------
// out(M,N) = A(M,K) @ W(N,K)^T + bias; A,W fragment-tiled; 128x128 tile.
// EPI: 0=store f32 row-major (tok,H);  1=QKV split (Q,K tiled per-bh, V rowmaj);
//      2=+residual f32 row-major;      3=GELU -> tiled bf16 [M,1024]
template<int EPI, int K>
__global__ __launch_bounds__(256) void k_gemm(const u16* __restrict__ A,
    const u16* __restrict__ W, const float* __restrict__ bias,
    const float* __restrict__ res, float* __restrict__ oF,
    u16* __restrict__ o0, u16* __restrict__ o1, u16* __restrict__ o2){
  constexpr int KT = K/32;
  int tid=threadIdx.x; int w=tid>>6; int wr=w>>1, wc=w&1;
  int la=tid&63, lq=la>>4, lr=la&15;
  int rb=blockIdx.x*128+wr*64, cb=blockIdx.y*128+wc*64;
  f32x4 acc[4][4];
  #pragma unroll
  for(int mt=0;mt<4;++mt)
    #pragma unroll
    for(int nt=0;nt<4;++nt) acc[mt][nt]=f32x4{0.f,0.f,0.f,0.f};
  const u16* Ap = A + (size_t)(rb>>4)*KT*512 + la*8;
  const u16* Wp = W + (size_t)(cb>>4)*KT*512 + la*8;
  #pragma unroll 8
  for(int kk=0;kk<KT;++kk){
    s16x8 aF[4], bF[4];
    #pragma unroll
    for(int mt=0;mt<4;++mt) aF[mt]=*(const s16x8*)(Ap + (size_t)(mt*KT+kk)*512);
    #pragma unroll
    for(int nt=0;nt<4;++nt) bF[nt]=*(const s16x8*)(Wp + (size_t)(nt*KT+kk)*512);
    #pragma unroll
    for(int mt=0;mt<4;++mt)
      #pragma unroll
      for(int nt=0;nt<4;++nt) acc[mt][nt]=mfma16(aF[mt],bF[nt],acc[mt][nt]);
  }
  #pragma unroll
  for(int mt=0;mt<4;++mt){
    #pragma unroll
    for(int nt=0;nt<4;++nt){
      int col = cb+nt*16+lr;
      float bv = bias[col];
      #pragma unroll
      for(int i=0;i<4;++i){
        int row = rb+mt*16+lq*4+i;           // = tok for activations
        float v = acc[mt][nt][i]+bv;
        if constexpr(EPI==0){
          oF[(size_t)row*256+col]=v;         // row-major (tok,H) == (T,B,H)
        } else if constexpr(EPI==1){
          int sec=col>>8; int hcol=col&255; int head=hcol>>6, d=hcol&63;
          int t=row>>4, b=row&15, bh=b*4+head;
          u16 q=f2bf_cvt(v);
          if(sec==2){
            o2[(size_t)bh*65536 + (size_t)t*64 + d]=q;   // V row-major
          } else {
            size_t adr=(size_t)bh*65536 + tadr(t,d,2);   // Q/K tiled [1024,64]
            (sec? o1 : o0)[adr]=q;
          }
        } else if constexpr(EPI==2){
          size_t adr=(size_t)row*256+col;
          oF[adr]=v+res[adr];
        } else {
          o0[tadr(row,col,32)]=f2bf_cvt(geluf(v));       // ff1 tiled [M,1024]
        }
      }
    }
  }
}

// ------------------------------- LNN scan -----------------------------------
// 1 workgroup, 8 waves. Raw barrier (lgkmcnt only) -> global stores free-fly.
__global__ __launch_bounds__(512) void k_scan(const float* __restrict__ ip,
    const float* __restrict__ W_rec, const float* __restrict__ tau,
    float* __restrict__ seqF){
  __shared__ u16 hbuf[2][4096];
  int tid=threadIdx.x, w=tid>>6, la=tid&63, lq=la>>4, lr=la&15;
  for(int i=tid;i<8192;i+=512) ((u16*)hbuf)[i]=0;
  int col[2]; float aC[2];
  s16x8 bF[2][8];
  #pragma unroll
  for(int nt=0;nt<2;++nt){
    int c = w*32+nt*16+lr; col[nt]=c;
    aC[nt] = 1.f - 0.1f/tau[c];
    for(int kk=0;kk<8;++kk){
      s16x8 f;
      #pragma unroll
      for(int j=0;j<8;++j){ int k=kk*32+lq*8+j; f[j]=(short)f2bf_cvt(W_rec[(size_t)k*256+c]); }
      bF[nt][kk]=f;
    }
  }
  float hC[2][4]={{0,0,0,0},{0,0,0,0}};
  const float* ipb = ip + lq*1024 + col[0];   // +i*256 +nt*16 per elem
  float* sp = seqF + lq*1024 + col[0];
  float ipc[2][4], ip1[2][4];
  #pragma unroll
  for(int nt=0;nt<2;++nt)
    #pragma unroll
    for(int i=0;i<4;++i){ ipc[nt][i]=ipb[i*256+nt*16]; ip1[nt][i]=ipb[4096+i*256+nt*16]; }
  __syncthreads();
  #pragma unroll 2
  for(int t=0;t<1024;++t){
    const char* rbuf = (const char*)hbuf + (t&1)*8192;
    char* wbuf = (char*)hbuf + ((t+1)&1)*8192;
    s16x8 aF[8];
    #pragma unroll
    for(int kk=0;kk<8;++kk){
      int off = (lr*512 + kk*64 + lq*16) ^ ((lr&7)<<4);
      aF[kk]=*(const s16x8*)(rbuf+off);
    }
    // prefetch ip(t+2)
    int tn = (t<1022)? t+2 : 1023;
    const float* ipp = ipb + (size_t)tn*4096;
    float ipn[2][4];
    #pragma unroll
    for(int nt=0;nt<2;++nt)
      #pragma unroll
      for(int i=0;i<4;++i) ipn[nt][i]=ipp[i*256+nt*16];
    f32x4 p0={0.f,0.f,0.f,0.f},p1={0.f,0.f,0.f,0.f};
    f32x4 q0={0.f,0.f,0.f,0.f},q1={0.f,0.f,0.f,0.f};
    #pragma unroll
    for(int kk=0;kk<4;++kk){
      p0=mfma16(aF[2*kk],  bF[0][2*kk],  p0);
      p1=mfma16(aF[2*kk+1],bF[0][2*kk+1],p1);
      q0=mfma16(aF[2*kk],  bF[1][2*kk],  q0);
      q1=mfma16(aF[2*kk+1],bF[1][2*kk+1],q1);
    }
    #pragma unroll
    for(int nt=0;nt<2;++nt){
      #pragma unroll
      for(int i=0;i<4;++i){
        float am = nt ? (q0[i]+q1[i]) : (p0[i]+p1[i]);
        float s = ipc[nt][i]+am;
        float e = __expf(2.f*s);                                  // inf-safe
        float f = __builtin_fmaf(-2.f, __builtin_amdgcn_rcpf(e+1.f), 1.f); // tanh
        float hn = __builtin_fmaf(0.1f, f, aC[nt]*hC[nt][i]);
        hn = __builtin_amdgcn_fmed3f(hn,-10.f,10.f);
        hC[nt][i]=hn;
        sp[i*256+nt*16]=hn;
        u16 hb=f2bf_cvt(hn);
        int b = lq*4+i;
        int woff = (b*512 + col[nt]*2) ^ ((b&7)<<4);
        *(u16*)(wbuf+woff)=hb;
        ipc[nt][i]=ip1[nt][i];
        ip1[nt][i]=ipn[nt][i];
      }
    }
    sp += 4096;
    asm volatile("s_waitcnt lgkmcnt(0)\n\ts_barrier" ::: "memory");
  }
}

// --------------------- seqF f32 -> seqB tiled bf16 ---------------------------
__global__ __launch_bounds__(256) void k_cvt(const float* __restrict__ in,
    u16* __restrict__ out){
  int tid=threadIdx.x; int tr=blockIdx.x; int tk=tid>>5;
  int tok0=tr*16;
  #pragma unroll
  for(int rep=0;rep<2;++rep){
    int la=(tid&31)+rep*32;
    const float* p = in + (size_t)(tok0+(la&15))*256 + tk*32 + (la>>4)*8;
    f32x4 v0=*(const f32x4*)p, v1=*(const f32x4*)(p+4);
    s16x8 o;
    #pragma unroll
    for(int j=0;j<4;++j){ o[j]=(short)f2bf_cvt(v0[j]); o[j+4]=(short)f2bf_cvt(v1[j]); }
    *(s16x8*)(out + ((size_t)tr*8+tk)*512 + la*8) = o;
  }
}

// ----------------------------- V transpose -> VT tiled -----------------------
__global__ __launch_bounds__(256) void k_vt(const u16* __restrict__ V, u16* __restrict__ VT){
  __shared__ u16 tile[128][66];
  int tid=threadIdx.x; int bh=blockIdx.y, tc=blockIdx.x;   // tc: 8 chunks of 128 t
  const u16* Vb = V + (size_t)bh*65536 + (size_t)tc*128*64;
  #pragma unroll
  for(int r=0;r<4;++r){
    int t=(tid>>3)+r*32, d0=(tid&7)*8;
    *(u16x8*)&tile[t][d0] = *(const u16x8*)(Vb + t*64 + d0);
  }
  __syncthreads();
  u16* O = VT + (size_t)bh*65536 + (size_t)tc*4*512;
  #pragma unroll
  for(int wi=0;wi<4;++wi){
    int ti = (tid>>6) + wi*4;          // 16 output tiles: tr=d>>4 (4) x tkl (4)
    int tr = ti&3, tkl = ti>>2;
    int la2 = tid&63;
    int trow = tkl*32 + (la2>>4)*8;
    int d = tr*16 + (la2&15);
    u16x8 o;
    #pragma unroll
    for(int j=0;j<8;++j) o[j]=tile[trow+j][d];
    *(u16x8*)(O + (size_t)tr*32*512 + (size_t)tkl*512 + la2*8) = o;
  }
}

// ------------------------------ attention -----------------------------------
__global__ __launch_bounds__(256) void k_attn(const u16* __restrict__ Q,
    const u16* __restrict__ K, const u16* __restrict__ VT, u16* __restrict__ ctx){
  __shared__ u16 pbuf[4][1024];
  int tid=threadIdx.x, w=tid>>6, la=tid&63, lq=la>>4, lr=la&15;
  int bh=blockIdx.y, qb=blockIdx.x;
  char* pwc = (char*)pbuf + w*2048;
  const u16* Qbh = Q + (size_t)bh*65536;
  const u16* Kbh = K + (size_t)bh*65536;
  const u16* Vbh = VT + (size_t)bh*65536;
  int trq = qb*4 + w;
  s16x8 qF0=*(const s16x8*)(Qbh + (size_t)(trq*2  )*512 + la*8);
  s16x8 qF1=*(const s16x8*)(Qbh + (size_t)(trq*2+1)*512 + la*8);
  f32x4 O[4];
  #pragma unroll
  for(int nt=0;nt<4;++nt) O[nt]=f32x4{0.f,0.f,0.f,0.f};
  float m_run=-1e30f, l_run=0.f;
  for(int kvb=0;kvb<16;++kvb){
    f32x4 sa[4];
    #pragma unroll
    for(int mt=0;mt<4;++mt){
      int trk = kvb*4+mt;
      s16x8 k0=*(const s16x8*)(Kbh + (size_t)(trk*2  )*512 + la*8);
      s16x8 k1=*(const s16x8*)(Kbh + (size_t)(trk*2+1)*512 + la*8);
      f32x4 a=f32x4{0.f,0.f,0.f,0.f};
      a=mfma16(k0,qF0,a); a=mfma16(k1,qF1,a);
      sa[mt]=a;
    }
    float p[4][4]; float pm=-1e30f;
    #pragma unroll
    for(int mt=0;mt<4;++mt)
      #pragma unroll
      for(int i=0;i<4;++i){ p[mt][i]=sa[mt][i]*0.125f; pm=fmaxf(pm,p[mt][i]); }
    pm=fmaxf(pm,__shfl_xor(pm,16,64));
    pm=fmaxf(pm,__shfl_xor(pm,32,64));
    float mnew=fmaxf(m_run,pm);
    float c=__expf(m_run-mnew);
    float ps=0.f;
    #pragma unroll
    for(int mt=0;mt<4;++mt)
      #pragma unroll
      for(int i=0;i<4;++i){ p[mt][i]=__expf(p[mt][i]-mnew); ps+=p[mt][i]; }
    ps+=__shfl_xor(ps,16,64);
    ps+=__shfl_xor(ps,32,64);
    l_run=l_run*c+ps; m_run=mnew;
    #pragma unroll
    for(int i=0;i<4;++i){
      float ci=__shfl(c, lq*4+i, 64);
      #pragma unroll
      for(int nt=0;nt<4;++nt) O[nt][i]*=ci;
    }
    #pragma unroll
    for(int mt=0;mt<4;++mt){
      u16x4 pk;
      #pragma unroll
      for(int i=0;i<4;++i) pk[i]=f2bf_cvt(p[mt][i]);
      int off = (lr*128 + mt*32 + lq*8) ^ ((lr&7)<<4);
      *(u16x4*)(pwc+off)=pk;
    }
    #pragma unroll
    for(int kk2=0;kk2<2;++kk2){
      int off = (lr*128 + kk2*64 + lq*16) ^ ((lr&7)<<4);
      s16x8 pA = *(const s16x8*)(pwc+off);
      #pragma unroll
      for(int nt=0;nt<4;++nt){
        s16x8 vF = *(const s16x8*)(Vbh + (size_t)(nt*32 + kvb*2 + kk2)*512 + la*8);
        O[nt]=mfma16(pA, vF, O[nt]);
      }
    }
  }
  int b=bh>>2, head=bh&3;
  #pragma unroll
  for(int i=0;i<4;++i){
    float li=__shfl(l_run, lq*4+i, 64);
    float inv=1.f/li;
    int t = qb*64 + w*16 + lq*4 + i;
    int tok = t*16 + b;
    #pragma unroll
    for(int nt=0;nt<4;++nt){
      int colc = head*64 + nt*16 + lr;
      ctx[tadr(tok,colc,8)] = f2bf_cvt(O[nt][i]*inv);   // tiled [16384,256]
    }
  }
}

// ------------------------------- LayerNorm ----------------------------------
__global__ __launch_bounds__(256) void k_ln(const float* __restrict__ in,
    const float* __restrict__ g, const float* __restrict__ bt,
    float* __restrict__ outF, u16* __restrict__ outB){
  int tid=threadIdx.x; int w=tid>>6; int la=tid&63;
  int tr=blockIdx.x;
  f32x4 gv=*(const f32x4*)(g+la*4), tv=*(const f32x4*)(bt+la*4);
  #pragma unroll
  for(int it=0;it<4;++it){
    int tok = tr*16 + w*4 + it;
    f32x4 v = *(const f32x4*)(in + (size_t)tok*256 + la*4);
    float s=v[0]+v[1]+v[2]+v[3];
    s=wave_sum64(s);
    float m=s*(1.f/256.f);
    float ss=0.f;
    #pragma unroll
    for(int j=0;j<4;++j){ v[j]-=m; ss+=v[j]*v[j]; }
    ss=wave_sum64(ss);
    float rs=rsqrtf(ss*(1.f/256.f)+1e-5f);
    f32x4 o; u16x4 ob;
    #pragma unroll
    for(int j=0;j<4;++j){ o[j]=v[j]*rs*gv[j]+tv[j]; ob[j]=f2bf_cvt(o[j]); }
    *(f32x4*)(outF + (size_t)tok*256 + la*4)=o;
    int off = (tr*8 + (la>>3))*512 + (((la>>1)&3)*16 + (tok&15))*8 + (la&1)*4;
    *(u16x4*)(outB+off)=ob;
  }
}

// ------------------------------- pool + fc ----------------------------------
__global__ __launch_bounds__(256) void k_pool(const float* __restrict__ seqF,
    const float* __restrict__ W_fc, const float* __restrict__ b_fc,
    float* __restrict__ out){
  int tid=threadIdx.x; int b=blockIdx.y; int t0=blockIdx.x*128;
  float s=0.f;
  for(int tt=0;tt<128;++tt) s += seqF[(size_t)((t0+tt)*16 + b)*256 + tid];
  float v = s * W_fc[tid];
  v = wave_sum64(v);
  __shared__ float red[4];
  if((tid&63)==0) red[tid>>6]=v;
  __syncthreads();
  if(tid==0){
    float tot=red[0]+red[1]+red[2]+red[3];
    atomicAdd(out+b, tot*(1.f/1024.f));
    if(blockIdx.x==0) atomicAdd(out+b, b_fc[0]);
  }
}

// ------------------------------- launch -------------------------------------
extern "C" void kernel_launch(void* const* d_in, const int* in_sizes, int n_in,
                              void* d_out, int out_size, void* d_ws, size_t ws_size,
                              hipStream_t stream){
  const float* x      =(const float*)d_in[0];
  const float* W_in   =(const float*)d_in[1];
  const float* b_in   =(const float*)d_in[2];
  const float* ln_in_g=(const float*)d_in[3];
  const float* ln_in_b=(const float*)d_in[4];
  const float* W_x    =(const float*)d_in[5];
  const float* b_x    =(const float*)d_in[6];
  const float* tau    =(const float*)d_in[7];
  const float* W_rec  =(const float*)d_in[8];
  const float* Wqkv   =(const float*)d_in[9];
  const float* bqkv   =(const float*)d_in[10];
  const float* Wo     =(const float*)d_in[11];
  const float* bo     =(const float*)d_in[12];
  const float* ln1_g  =(const float*)d_in[13];
  const float* ln1_b  =(const float*)d_in[14];
  const float* W1     =(const float*)d_in[15];
  const float* b1     =(const float*)d_in[16];
  const float* W2     =(const float*)d_in[17];
  const float* b2     =(const float*)d_in[18];
  const float* ln2_g  =(const float*)d_in[19];
  const float* ln2_b  =(const float*)d_in[20];
  const float* W_fc   =(const float*)d_in[21];
  const float* b_fc   =(const float*)d_in[22];
  float* out=(float*)d_out;

  char* ws=(char*)d_ws;
  const size_t MB=1ull<<20;
  float* ip   =(float*)(ws);             // also rawO
  float* rawO = ip;
  float* seqF =(float*)(ws+16*MB);
  u16*   seqB =(u16*)  (ws+32*MB);
  u16*   Qb   =(u16*)  (ws+40*MB);
  u16*   Kb   =(u16*)  (ws+48*MB);
  u16*   Vb   =(u16*)  (ws+56*MB);
  u16*   VTb  =(u16*)  (ws+64*MB);
  u16*   ff1  =(u16*)  (ws+40*MB);       // reuses Q..VT after attention
  u16*   ctx  =(u16*)  (ws+72*MB);
  u16*   wb   =(u16*)  (ws+80*MB);

  hipMemsetAsync(d_out, 0, 16*sizeof(float), stream);
  k_wconv<<<800, 256, 0, stream>>>(W_x, Wqkv, Wo, W1, W2, wb);
  k_input<<<4096, 256, 0, stream>>>(x, W_in, b_in, ln_in_g, ln_in_b, seqB);
  // ip = u @ W_x^T + b_x, stored (tok,H) f32 row-major == (T,B,H)
  k_gemm<0,256><<<dim3(128,2), 256, 0, stream>>>(seqB, wb+WB_WX, b_x, nullptr, ip, nullptr, nullptr, nullptr);
  k_scan<<<1, 512, 0, stream>>>(ip, W_rec, tau, seqF);
  k_cvt <<<1024, 256, 0, stream>>>(seqF, seqB);

  for(int ly=0; ly<2; ++ly){
    k_gemm<1,256><<<dim3(128,6), 256, 0, stream>>>(seqB, wb+WB_WQKV+ly*196608, bqkv+ly*768, nullptr, nullptr, Qb, Kb, Vb);
    k_vt  <<<dim3(8,64), 256, 0, stream>>>(Vb, VTb);
    k_attn<<<dim3(16,64), 256, 0, stream>>>(Qb, Kb, VTb, ctx);
    k_gemm<2,256><<<dim3(128,2), 256, 0, stream>>>(ctx, wb+WB_WO+ly*65536, bo+ly*256, seqF, rawO, nullptr, nullptr, nullptr);
    k_ln  <<<1024, 256, 0, stream>>>(rawO, ln1_g+ly*256, ln1_b+ly*256, seqF, seqB);
    k_gemm<3,256><<<dim3(128,8), 256, 0, stream>>>(seqB, wb+WB_W1+ly*262144, b1+ly*1024, nullptr, nullptr, ff1, nullptr, nullptr);
    k_gemm<2,1024><<<dim3(128,2), 256, 0, stream>>>(ff1, wb+WB_W2+ly*262144, b2+ly*256, seqF, rawO, nullptr, nullptr, nullptr);
    k_ln  <<<1024, 256, 0, stream>>>(rawO, ln2_g+ly*256, ln2_b+ly*256, seqF, seqB);
  }
  k_pool<<<dim3(8,16), 256, 0, stream>>>(seqF, W_fc, b_fc, out);
}